// Round 8
// baseline (513.825 us; speedup 1.0000x reference)
//
#include <hip/hip_runtime.h>
#include <stdint.h>

#define NN 100000
#define NE 1600000
#define NBUK 782   // ceil(NN/128)
#define G 256      // pass-1/2 blocks
#define CHUNK 6250 // NE / G

typedef unsigned int u32;
typedef unsigned short u16;
typedef short v8s __attribute__((ext_vector_type(8)));
typedef float v4f __attribute__((ext_vector_type(4)));

union U4S8 {
    uint4 u;
    v8s s;
};

__device__ __forceinline__ float bf2f(u16 u) {
    return __uint_as_float(((u32)u) << 16);
}
__device__ __forceinline__ u16 f2bf(float f) {
    u32 u = __float_as_uint(f);
    u = u + 0x7FFFu + ((u >> 16) & 1u);
    return (u16)(u >> 16);
}
__device__ __forceinline__ float lo16(u32 u) { return __uint_as_float(u << 16); }
__device__ __forceinline__ float hi16(u32 u) {
    return __uint_as_float(u & 0xFFFF0000u);
}

// ---------------- dtype detection ----------------
__global__ void detect_kernel(const u32* __restrict__ ei,
                              const u32* __restrict__ x, int* flags) {
    __shared__ int bad64, badbf;
    int t = threadIdx.x;
    if (t == 0) { bad64 = 0; badbf = 0; }
    __syncthreads();
    if (ei[2 * t + 1] != 0u) atomicAdd(&bad64, 1);
    u32 d = x[t];
    u32 e = (d >> 7) & 0xFFu;
    if (e != 0u && (e < 96u || e > 160u)) atomicAdd(&badbf, 1);
    __syncthreads();
    if (t == 0) {
        flags[0] = (bad64 < 16) ? 1 : 0;
        flags[1] = (badbf < 16) ? 1 : 0;
    }
}

// ---------------- prep: x -> bf16 (+ zero pad row NN of xb,h1,h2) ----------
__global__ void conv_x(const void* __restrict__ x, const int* __restrict__ flags,
                       u32* __restrict__ xb, u32* __restrict__ h1,
                       u32* __restrict__ h2) {
    int i = blockIdx.x * 256 + threadIdx.x;
    if (i >= NN * 64) {
        int p = i - NN * 64;
        if (p < 64) {
            xb[NN * 64 + p] = 0;
            h1[NN * 64 + p] = 0;
            h2[NN * 64 + p] = 0;
        }
        return;
    }
    u32 o;
    if (flags[1]) {
        o = ((const u32*)x)[i];
    } else {
        float2 v = ((const float2*)x)[i];
        o = ((u32)f2bf(v.y) << 16) | (u32)f2bf(v.x);
    }
    xb[i] = o;
}

// ---------------- prep: WT[c][k] = (k<128?Wr:Wl)[k%128][c], bias->f32 ----------
__global__ void wt_prep_all(const void* __restrict__ Wr0,
                            const void* __restrict__ Wl0,
                            const void* __restrict__ b0,
                            const void* __restrict__ Wr1,
                            const void* __restrict__ Wl1,
                            const void* __restrict__ b1,
                            const void* __restrict__ Wr2,
                            const void* __restrict__ Wl2,
                            const void* __restrict__ b2,
                            const int* __restrict__ flags,
                            u16* __restrict__ WT0, float* __restrict__ bf0,
                            u16* __restrict__ WT1, float* __restrict__ bf1,
                            u16* __restrict__ WT2, float* __restrict__ bf2_) {
    const void* Wr;
    const void* Wl;
    const void* bias;
    u16* WT;
    float* bias_f;
    int cout, t;
    if (blockIdx.x < 128) {
        Wr = Wr0; Wl = Wl0; bias = b0; WT = WT0; bias_f = bf0; cout = 128;
        t = blockIdx.x * 256 + threadIdx.x;
    } else if (blockIdx.x < 256) {
        Wr = Wr1; Wl = Wl1; bias = b1; WT = WT1; bias_f = bf1; cout = 128;
        t = (blockIdx.x - 128) * 256 + threadIdx.x;
    } else {
        Wr = Wr2; Wl = Wl2; bias = b2; WT = WT2; bias_f = bf2_; cout = 64;
        t = (blockIdx.x - 256) * 256 + threadIdx.x;
    }
    if (t < 256 * cout) {
        int k = t / cout, c = t % cout;
        const void* W = (k < 128) ? Wr : Wl;
        int kk = k & 127;
        float v;
        if (flags[1])
            v = bf2f(((const u16*)W)[kk * cout + c]);
        else
            v = ((const float*)W)[kk * cout + c];
        WT[c * 256 + k] = f2bf(v);
    }
    if (t < cout) {
        bias_f[t] =
            flags[1] ? bf2f(((const u16*)bias)[t]) : ((const float*)bias)[t];
    }
}

// ---------------- bucketed CSR build ----------------
__global__ __launch_bounds__(256) void p1_hist(const void* __restrict__ ei,
                                               const int* __restrict__ flags,
                                               int* __restrict__ hist) {
    __shared__ int h[NBUK];
    int g = blockIdx.x, t = threadIdx.x;
    for (int b = t; b < NBUK; b += 256) h[b] = 0;
    __syncthreads();
    int e0 = g * CHUNK;
    int e1 = e0 + CHUNK;
    const int* p = (const int*)ei;
    if (flags[0]) {
        for (int e = e0 + t; e < e1; e += 256)
            atomicAdd(&h[p[2 * (NE + e)] >> 7], 1);
    } else {
        for (int e = e0 + t; e < e1; e += 256)
            atomicAdd(&h[p[NE + e] >> 7], 1);
    }
    __syncthreads();
    for (int b = t; b < NBUK; b += 256) hist[b * G + g] = h[b];
}

__global__ void scan_block_g(const int* __restrict__ in, int* __restrict__ out,
                             int* __restrict__ bsums, int n) {
    __shared__ int sS[256];
    int t = threadIdx.x;
    int base = blockIdx.x * 1024 + t * 4;
    int c[4];
#pragma unroll
    for (int i = 0; i < 4; ++i) c[i] = (base + i < n) ? in[base + i] : 0;
    int s = c[0] + c[1] + c[2] + c[3];
    sS[t] = s;
    __syncthreads();
    for (int dlt = 1; dlt < 256; dlt <<= 1) {
        int v = (t >= dlt) ? sS[t - dlt] : 0;
        __syncthreads();
        sS[t] += v;
        __syncthreads();
    }
    int run = sS[t] - s;
    if (t == 255) bsums[blockIdx.x] = sS[255];
#pragma unroll
    for (int i = 0; i < 4; ++i) {
        if (base + i < n) out[base + i] = run;
        run += c[i];
    }
}

__global__ void scan_top_g(int* bsums, int nb) {
    __shared__ int sS[256];
    int t = threadIdx.x;
    int v = (t < nb) ? bsums[t] : 0;
    sS[t] = v;
    __syncthreads();
    for (int d = 1; d < 256; d <<= 1) {
        int u = (t >= d) ? sS[t - d] : 0;
        __syncthreads();
        sS[t] += u;
        __syncthreads();
    }
    if (t < nb) bsums[t] = sS[t] - v;
}

__global__ void scan_add_g(int* __restrict__ out, const int* __restrict__ bsums,
                           int n) {
    int i = blockIdx.x * 256 + threadIdx.x;
    if (i < n) out[i] += bsums[i >> 10];
}

__global__ __launch_bounds__(256) void p2_scatter(const void* __restrict__ ei,
                                                  const int* __restrict__ flags,
                                                  const int* __restrict__ histS,
                                                  int2* __restrict__ ebuf) {
    __shared__ int cur[NBUK];
    int g = blockIdx.x, t = threadIdx.x;
    for (int b = t; b < NBUK; b += 256) cur[b] = histS[b * G + g];
    __syncthreads();
    int e0 = g * CHUNK;
    int e1 = e0 + CHUNK;
    const int* p = (const int*)ei;
    int is64 = flags[0];
    for (int e = e0 + t; e < e1; e += 256) {
        int s, d;
        if (is64) {
            s = p[2 * e];
            d = p[2 * (NE + e)];
        } else {
            s = p[e];
            d = p[NE + e];
        }
        int pos = atomicAdd(&cur[d >> 7], 1);
        ebuf[pos] = make_int2(s, d);
    }
}

__global__ __launch_bounds__(256) void p3_build(const int* __restrict__ histS,
                                                const int2* __restrict__ ebuf,
                                                int* __restrict__ off,
                                                int* __restrict__ ssrc) {
    __shared__ int cnt[128], pref[128], cur[128];
    int b = blockIdx.x, t = threadIdx.x;
    int node0 = b << 7;
    int bs = histS[b * G];
    int be = (b == NBUK - 1) ? NE : histS[(b + 1) * G];
    if (t < 128) cnt[t] = 0;
    __syncthreads();
    for (int e = bs + t; e < be; e += 256)
        atomicAdd(&cnt[ebuf[e].y - node0], 1);
    __syncthreads();
    if (t < 128) pref[t] = cnt[t];
    __syncthreads();
    for (int d = 1; d < 128; d <<= 1) {
        int v = 0;
        if (t < 128 && t >= d) v = pref[t - d];
        __syncthreads();
        if (t < 128) pref[t] += v;
        __syncthreads();
    }
    if (t < 128) {
        int ex = pref[t] - cnt[t];
        cur[t] = ex;
        int node = node0 + t;
        if (node < NN) off[node] = bs + ex;
    }
    if (b == NBUK - 1 && t == 0) off[NN] = NE;
    __syncthreads();
    for (int e = bs + t; e < be; e += 256) {
        int2 sd = ebuf[e];
        int pos = atomicAdd(&cur[sd.y - node0], 1);
        ssrc[bs + pos] = sd.x;
    }
}

// ---------------- mean aggregation (gather, bf16 in/out) ----------------
__global__ __launch_bounds__(256) void gather_mean_b(
    const u32* __restrict__ feat, const int* __restrict__ off,
    const int* __restrict__ ssrc, u32* __restrict__ meanB) {
    int node = blockIdx.x * 4 + (threadIdx.x >> 6);
    int lane = threadIdx.x & 63;
    int o0 = __builtin_amdgcn_readfirstlane(off[node]);
    int o1 = __builtin_amdgcn_readfirstlane(off[node + 1]);
    int cnt = o1 - o0;
    float a0 = 0.f, a1 = 0.f;
    for (int base = 0; base < cnt; base += 64) {
        int lim = cnt - base;
        if (lim > 64) lim = 64;
        int myidx = (lane < lim) ? ssrc[o0 + base + lane] : NN;
        int jb = (lim + 15) & ~15;
        for (int j = 0; j < jb; j += 16) {
            u32 uu[16];
#pragma unroll
            for (int q = 0; q < 16; ++q) {
                int sidx = __builtin_amdgcn_readlane(myidx, j + q);
                uu[q] = feat[(size_t)sidx * 64 + lane];
            }
#pragma unroll
            for (int q = 0; q < 16; ++q) {
                a0 += lo16(uu[q]);
                a1 += hi16(uu[q]);
            }
        }
    }
    float inv = 1.0f / (float)(cnt > 0 ? cnt : 1);
    meanB[node * 64 + lane] =
        ((u32)f2bf(a1 * inv) << 16) | (u32)f2bf(a0 * inv);
}

// ---------------- MFMA GEMM v2: out = [self|mean](bf16) @ WT^T + b ----------
// Block: 64 rows (4 waves x 16 rows), all COUT cols per wave (NT tiles).
// All 8 A-frags preloaded at entry (32 VGPR, one vmcnt drain). Inner: loop
// over col-tiles; per nt, 8 L1/L2-hot B-loads overlap previous nt's MFMA
// chain under full unroll. launch_bounds(256,4) caps VGPR at 128.
template <int COUT, bool RELU, bool FINAL>
__global__ __launch_bounds__(256, 4) void sage_mfma(
    const u16* __restrict__ selfB, const u16* __restrict__ meanB,
    const u16* __restrict__ WT, const float* __restrict__ bias_f,
    void* __restrict__ out, const int* __restrict__ flags) {
    constexpr int NT = COUT / 16;
    const int tid = threadIdx.x;
    const int wave = tid >> 6;
    const int lane = tid & 63;
    const int n16 = lane & 15;
    const int quad = lane >> 4;
    const int rowbase = blockIdx.x * 64 + wave * 16;
    const int bfin = flags[1];

    int ar = rowbase + n16;
    ar = (ar < NN) ? ar : (NN - 1);

    const u16* aS = selfB + (size_t)ar * 128 + quad * 8;
    const u16* aM = meanB + (size_t)ar * 128 + quad * 8;
    const u16* bp = WT + (size_t)n16 * 256 + quad * 8;

    // preload all A fragments: ks 0..3 self, 4..7 mean
    U4S8 a[8];
#pragma unroll
    for (int ks = 0; ks < 4; ++ks) {
        a[ks].u = *(const uint4*)(aS + ks * 32);
        a[4 + ks].u = *(const uint4*)(aM + ks * 32);
    }

    v4f acc[NT];
#pragma unroll
    for (int nt = 0; nt < NT; ++nt) acc[nt] = (v4f)(0.f);

#pragma unroll
    for (int nt = 0; nt < NT; ++nt) {
        U4S8 b[8];
#pragma unroll
        for (int ks = 0; ks < 8; ++ks)
            b[ks].u = *(const uint4*)(bp + nt * 16 * 256 + ks * 32);
#pragma unroll
        for (int ks = 0; ks < 8; ++ks)
            acc[nt] = __builtin_amdgcn_mfma_f32_16x16x32_bf16(a[ks].s, b[ks].s,
                                                              acc[nt], 0, 0, 0);
    }

    // epilogue: C/D layout col=lane&15, row=quad*4+reg
#pragma unroll
    for (int nt = 0; nt < NT; ++nt) {
        const int c = nt * 16 + n16;
        const float bv = bias_f[c];
#pragma unroll
        for (int r = 0; r < 4; ++r) {
            int row = rowbase + quad * 4 + r;
            if (row < NN) {
                float v = acc[nt][r] + bv;
                if (RELU) v = fmaxf(v, 0.f);
                if (FINAL && !bfin)
                    ((float*)out)[(size_t)row * COUT + c] = v;
                else
                    ((u16*)out)[(size_t)row * COUT + c] = f2bf(v);
            }
        }
    }
}

extern "C" void kernel_launch(void* const* d_in, const int* in_sizes, int n_in,
                              void* d_out, int out_size, void* d_ws,
                              size_t ws_size, hipStream_t stream) {
    const void* x = d_in[0];
    const void* ei = d_in[1];
    const void* Wl0 = d_in[2];
    const void* Wr0 = d_in[3];
    const void* b0 = d_in[4];
    const void* Wl1 = d_in[5];
    const void* Wr1 = d_in[6];
    const void* b1 = d_in[7];
    const void* Wl2 = d_in[8];
    const void* Wr2 = d_in[9];
    const void* b2 = d_in[10];

    char* ws = (char*)d_ws;
    size_t o = 0;
    auto alloc = [&](size_t bytes) {
        void* p = ws + o;
        o = (o + bytes + 511) & ~(size_t)511;
        return p;
    };
    int* flags = (int*)alloc(16);
    int* hist = (int*)alloc((size_t)NBUK * G * 4);
    int* bsums = (int*)alloc(256 * 4);
    int* off = (int*)alloc((NN + 1) * 4);
    int* ssrc = (int*)alloc((size_t)NE * 4);
    int2* ebuf = (int2*)alloc((size_t)NE * 8);
    u32* xb = (u32*)alloc((size_t)(NN + 1) * 64 * 4);
    u32* meanB = (u32*)alloc((size_t)NN * 64 * 4);
    u32* h1 = (u32*)alloc((size_t)(NN + 1) * 64 * 4);
    u32* h2 = (u32*)alloc((size_t)(NN + 1) * 64 * 4);
    u16* WT0 = (u16*)alloc(256 * 128 * 2);
    u16* WT1 = (u16*)alloc(256 * 128 * 2);
    u16* WT2 = (u16*)alloc(256 * 64 * 2);
    float* bf0 = (float*)alloc(128 * 4);
    float* bf1 = (float*)alloc(128 * 4);
    float* bf2_ = (float*)alloc(64 * 4);

    constexpr int L = NBUK * G;              // 200192
    constexpr int NBLK = (L + 1023) / 1024;  // 196 (<= 256)
    constexpr int RB64 = (NN + 63) / 64;     // 1563

    detect_kernel<<<1, 256, 0, stream>>>((const u32*)ei, (const u32*)x, flags);
    conv_x<<<(NN * 64 + 64 + 255) / 256, 256, 0, stream>>>(x, flags, xb, h1,
                                                           h2);
    wt_prep_all<<<320, 256, 0, stream>>>(Wr0, Wl0, b0, Wr1, Wl1, b1, Wr2, Wl2,
                                         b2, flags, WT0, bf0, WT1, bf1, WT2,
                                         bf2_);

    // bucketed CSR build
    p1_hist<<<G, 256, 0, stream>>>(ei, flags, hist);
    scan_block_g<<<NBLK, 256, 0, stream>>>(hist, hist, bsums, L);
    scan_top_g<<<1, 256, 0, stream>>>(bsums, NBLK);
    scan_add_g<<<(L + 255) / 256, 256, 0, stream>>>(hist, bsums, L);
    p2_scatter<<<G, 256, 0, stream>>>(ei, flags, hist, ebuf);
    p3_build<<<NBUK, 256, 0, stream>>>(hist, ebuf, off, ssrc);

    // layer 0
    gather_mean_b<<<NN / 4, 256, 0, stream>>>(xb, off, ssrc, meanB);
    sage_mfma<128, true, false><<<RB64, 256, 0, stream>>>(
        (const u16*)xb, (const u16*)meanB, WT0, bf0, h1, flags);
    // layer 1
    gather_mean_b<<<NN / 4, 256, 0, stream>>>(h1, off, ssrc, meanB);
    sage_mfma<128, true, false><<<RB64, 256, 0, stream>>>(
        (const u16*)h1, (const u16*)meanB, WT1, bf1, h2, flags);
    // layer 2
    gather_mean_b<<<NN / 4, 256, 0, stream>>>(h2, off, ssrc, meanB);
    sage_mfma<64, false, true><<<RB64, 256, 0, stream>>>(
        (const u16*)h2, (const u16*)meanB, WT2, bf2_, d_out, flags);
}